// Round 11
// baseline (39.562 us; speedup 1.0000x reference)
//
#include <hip/hip_runtime.h>

// CenterLoss: loss = mean_b clip(||x_b - centers[labels[b]]||^2, 1e-12, 1e12)
//             + (C-1)*1e-12   (faithful replication of clipping the masked zeros)
//
// x: (8192,2048) f32   labels: (8192,) int   centers: (4096,2048) f32   out: scalar
//
// Structure: 32 KB memset of part[] + ONE kernel, 2048 blocks (EXACT machine
// capacity: 2048 blk x 256 thr = 256 CU x 2048 thr -- no straggler round).
//   - every block: 4 waves x 1 sample (proven R2 engine, fabric-bound at
//     ~6.6 TB/s on 128 MB logical); publish clipped distance to part[b] via
//     relaxed agent-scope atomic store (L2-bypass -> guaranteed visible).
//   - block 0 ONLY, after its own samples: parallel-sweep spinner. Each
//     round = 32 independent relaxed atomic loads per thread (accumulating,
//     low VGPR) + __syncthreads_and; sleep+retry if any entry still zero.
//     Data-as-flag (clip => every value >= 1e-12 > 0). Zero fences, zero RMWs.
//
// Constraint ledger: R8 no per-block agent fences / no modular tickets;
// R9 no same-address RMW per block (~10ns each, bunched 20us tail);
// R10 no extra block (straggler) + no serial dependent poll loads;
// R3/R4 engine restructurings are nulls -- engine kept byte-identical.

#define BATCH 8192
#define FEAT  2048
#define NCLS  4096
#define BLK   256
#define WAVES_PER_BLK (BLK / 64)              // 4
#define NBLK (BATCH / WAVES_PER_BLK)          // 2048
#define SWEEP (BATCH / BLK)                   // 32 entries per spinner thread

__global__ void __launch_bounds__(BLK, 8)     // cap 64 VGPR -> full residency
cl_all(const float* __restrict__ x,
       const int* __restrict__ labels,
       const float* __restrict__ centers,
       float* __restrict__ out,
       float* __restrict__ part) {
    const int tid  = threadIdx.x;
    const int wid  = tid >> 6;
    const int lane = tid & 63;
    const int bid  = blockIdx.x;
    const int b    = bid * WAVES_PER_BLK + wid;          // sample for this wave

    // ---------------- engine: one wave per sample ----------------
    const int lbl = labels[b];                           // wave-uniform

    const float4* __restrict__ xr =
        reinterpret_cast<const float4*>(x + (size_t)b * FEAT);
    const float4* __restrict__ cr =
        reinterpret_cast<const float4*>(centers + (size_t)lbl * FEAT);

    float acc0 = 0.0f, acc1 = 0.0f;
#pragma unroll
    for (int j = 0; j < FEAT / 4 / 64; ++j) {            // 8 iterations
        const int idx = lane + j * 64;
        const float4 xv = xr[idx];
        const float4 cv = cr[idx];
        const float d0 = xv.x - cv.x;
        const float d1 = xv.y - cv.y;
        const float d2 = xv.z - cv.z;
        const float d3 = xv.w - cv.w;
        acc0 += d0 * d0 + d1 * d1;
        acc1 += d2 * d2 + d3 * d3;
    }
    float acc = acc0 + acc1;

#pragma unroll
    for (int off = 32; off > 0; off >>= 1)
        acc += __shfl_down(acc, off, 64);

    if (lane == 0) {
        const float d = fminf(fmaxf(acc, 1e-12f), 1e12f);   // per-sample clip
        __hip_atomic_store(&part[b], d, __ATOMIC_RELAXED,
                           __HIP_MEMORY_SCOPE_AGENT);       // publish (L2-bypass)
    }

    if (bid != 0) return;

    // ---------------- block 0: parallel-sweep spinner finalize ----------------
    __shared__ float sred[WAVES_PER_BLK];

    float total_acc;
    for (;;) {
        bool ok = true;
        float a = 0.0f;
#pragma unroll
        for (int k = 0; k < SWEEP; ++k) {                // 32 independent loads
            const float v = __hip_atomic_load(&part[tid + k * BLK],
                                              __ATOMIC_RELAXED,
                                              __HIP_MEMORY_SCOPE_AGENT);
            ok &= (v != 0.0f);
            a  += v;
        }
        total_acc = a;
        if (__syncthreads_and(ok ? 1 : 0)) break;        // all 8192 published?
        __builtin_amdgcn_s_sleep(16);                    // ~1k cycles
    }

#pragma unroll
    for (int off = 32; off > 0; off >>= 1)
        total_acc += __shfl_down(total_acc, off, 64);
    if (lane == 0) sred[wid] = total_acc;
    __syncthreads();

    if (tid == 0) {
        const float total = sred[0] + sred[1] + sred[2] + sred[3];
        // masked-zero entries: (BATCH*NCLS - BATCH) * 1e-12 / BATCH
        out[0] = total / (float)BATCH + (float)(NCLS - 1) * 1e-12f;
    }
}

extern "C" void kernel_launch(void* const* d_in, const int* in_sizes, int n_in,
                              void* d_out, int out_size, void* d_ws, size_t ws_size,
                              hipStream_t stream) {
    const float* x       = (const float*)d_in[0];
    const int*   labels  = (const int*)d_in[1];
    const float* centers = (const float*)d_in[2];
    float* out  = (float*)d_out;
    float* part = (float*)d_ws;   // 8192 floats: zeroed, then fully overwritten

    (void)hipMemsetAsync(d_ws, 0, BATCH * sizeof(float), stream);
    cl_all<<<NBLK, BLK, 0, stream>>>(x, labels, centers, out, part);
}

// Round 12
// 25.687 us; speedup vs baseline: 1.5402x; 1.5402x over previous
//
#include <hip/hip_runtime.h>

// CenterLoss: loss = mean_b clip(||x_b - centers[labels[b]]||^2, 1e-12, 1e12)
//             + (C-1)*1e-12   (faithful replication of clipping the masked zeros)
//
// x:       (8192, 2048) f32
// labels:  (8192,)      int
// centers: (4096, 2048) f32
// out:     scalar f32
//
// FINAL CONFIG (best measured: 25.64 us, R4). Two kernels, no atomics, no
// fences, no tickets, no spinners.
//
// Evidence ledger (R1-R11):
//  - engine: one wave per sample, 128 MB logical (64 MB x from HBM + 64 MB
//    gathered centers from L3) at ~6.6 TB/s shared memory-side fabric =
//    19.4 us; this is ~96% of the fill-kernel ceiling (6.9 TB/s) measured
//    every round. MLP forcing (R3) and deeper pipelining (R4) were nulls ->
//    throughput-bound, not latency-bound.
//  - center dedupe (per-class waves): R6=95us, R7=81us — latency-hostile,
//    VGPR-squeezed, straggler-bound. Theoretical 6.5us traffic gain is not
//    harvestable with the structures available.
//  - single-kernel finalize: R8 ticket+agent-fences=137us (L2-writeback
//    serialization), R9 per-block same-address atomicAdd=44us (~10ns/RMW
//    bunched tail), R10/R11 spinners=33.8/39.6us (agent atomic loads
//    serialize). The ~6us two-kernel overhead is cheaper than every
//    fusion mechanism on this chip.
//
// Stage 1: 512 blocks x 4 waves; each wave streams 4 samples with a 2-deep
//          register pipeline (named buffers -> static indexing, no scratch).
// Stage 2: single block reduces the 8192 per-sample values (32 KB, L2-hot).

#define BATCH 8192
#define FEAT  2048
#define NCLS  4096
#define BLK   256
#define WAVES_PER_BLK (BLK / 64)                 // 4
#define NBLK 512
#define NWAVE (NBLK * WAVES_PER_BLK)             // 2048
#define SPW (BATCH / NWAVE)                      // 4 samples per wave

__global__ void __launch_bounds__(BLK)
cl_dist(const float* __restrict__ x,
        const int* __restrict__ labels,
        const float* __restrict__ centers,
        float* __restrict__ part) {
    const int tid  = threadIdx.x;
    const int wid  = tid >> 6;
    const int lane = tid & 63;
    const int gw   = blockIdx.x * WAVES_PER_BLK + wid;   // 0..2047
    const int b0   = gw * SPW;                           // first of 4 samples

    float4 xa[8], ca[8], xb[8], cb[8];

#define ISSUE(XBUF, CBUF, S)                                                   \
    {                                                                          \
        const float4* __restrict__ xr =                                        \
            reinterpret_cast<const float4*>(x + (size_t)(b0 + (S)) * FEAT);    \
        const int lbl = labels[b0 + (S)];                                      \
        const float4* __restrict__ cr =                                        \
            reinterpret_cast<const float4*>(centers + (size_t)lbl * FEAT);     \
        _Pragma("unroll")                                                      \
        for (int j = 0; j < 8; ++j) XBUF[j] = xr[lane + j * 64];               \
        _Pragma("unroll")                                                      \
        for (int j = 0; j < 8; ++j) CBUF[j] = cr[lane + j * 64];               \
    }

#define COMPUTE(XBUF, CBUF, S)                                                 \
    {                                                                          \
        float a0 = 0.0f, a1 = 0.0f;                                            \
        _Pragma("unroll")                                                      \
        for (int j = 0; j < 8; ++j) {                                          \
            const float d0 = XBUF[j].x - CBUF[j].x;                            \
            const float d1 = XBUF[j].y - CBUF[j].y;                            \
            const float d2 = XBUF[j].z - CBUF[j].z;                            \
            const float d3 = XBUF[j].w - CBUF[j].w;                            \
            a0 += d0 * d0 + d1 * d1;                                           \
            a1 += d2 * d2 + d3 * d3;                                           \
        }                                                                      \
        float acc = a0 + a1;                                                   \
        _Pragma("unroll")                                                      \
        for (int off = 32; off > 0; off >>= 1)                                 \
            acc += __shfl_down(acc, off, 64);                                  \
        if (lane == 0)                                                         \
            part[b0 + (S)] = fminf(fmaxf(acc, 1e-12f), 1e12f);                 \
    }

    // software pipeline over 4 samples, depth 2
    ISSUE(xa, ca, 0);
    ISSUE(xb, cb, 1);
    COMPUTE(xa, ca, 0);      // waits only on buf A (WAR deps keep order)
    ISSUE(xa, ca, 2);
    COMPUTE(xb, cb, 1);
    ISSUE(xb, cb, 3);
    COMPUTE(xa, ca, 2);
    COMPUTE(xb, cb, 3);

#undef ISSUE
#undef COMPUTE
}

__global__ void __launch_bounds__(BLK)
cl_final(const float* __restrict__ part, float* __restrict__ out) {
    const int tid = threadIdx.x;
    const float4* __restrict__ pr = reinterpret_cast<const float4*>(part);

    float acc = 0.0f;
#pragma unroll
    for (int j = 0; j < BATCH / 4 / BLK; ++j) {          // 8 iterations
        const float4 v = pr[tid + j * BLK];
        acc += (v.x + v.y) + (v.z + v.w);
    }

#pragma unroll
    for (int off = 32; off > 0; off >>= 1)
        acc += __shfl_down(acc, off, 64);

    __shared__ float s[BLK / 64];
    const int wid  = tid >> 6;
    const int lane = tid & 63;
    if (lane == 0) s[wid] = acc;
    __syncthreads();

    if (tid == 0) {
        const float total = s[0] + s[1] + s[2] + s[3];
        // masked-zero entries: (BATCH*NCLS - BATCH) * 1e-12 / BATCH
        out[0] = total / (float)BATCH + (float)(NCLS - 1) * 1e-12f;
    }
}

extern "C" void kernel_launch(void* const* d_in, const int* in_sizes, int n_in,
                              void* d_out, int out_size, void* d_ws, size_t ws_size,
                              hipStream_t stream) {
    const float* x       = (const float*)d_in[0];
    const int*   labels  = (const int*)d_in[1];
    const float* centers = (const float*)d_in[2];
    float* out  = (float*)d_out;
    float* part = (float*)d_ws;   // 8192 floats, fully overwritten every call

    cl_dist<<<NBLK, BLK, 0, stream>>>(x, labels, centers, part);
    cl_final<<<1, BLK, 0, stream>>>(part, out);
}